// Round 8
// baseline (174.374 us; speedup 1.0000x reference)
//
#include <hip/hip_runtime.h>

#define IS 256
#define FCOUNT 4096
#define NEARP 0.1f
#define FARP 100.0f
#define TINYF 1e-12f
#define CAP 256          // per-tile bin capacity (mean ~46, Poisson tail ≪ CAP)

// Value barrier: pins a value in a VGPR; no transform across it.
__device__ __forceinline__ float frn(float r) { asm("" : "+v"(r)); return r; }
__device__ __forceinline__ float mulrn(float a, float b) { return frn(a * b); }
__device__ __forceinline__ float addrn(float a, float b) { return frn(a + b); }
__device__ __forceinline__ float subrn(float a, float b) { return frn(a - b); }
__device__ __forceinline__ float divrn(float a, float b) { return frn(a / b); }
__device__ __forceinline__ float fmarn(float a, float b, float c) {
    return frn(__builtin_fmaf(a, b, c));
}

// ---------- pass 0: zero the per-tile counters ----------
__global__ void zero_counts(int* __restrict__ counts) {
    counts[blockIdx.x * 256 + threadIdx.x] = 0;
}

// ---------- pass 1: bin faces into 16x16-pixel tiles ----------
// Adaptive conservative dilation: fp-inside escape for a face is bounded by
// w_err*L/|det| (~2.5e-7/|det|); we use 1e-6/|det| (4x safety) + 2e-3 base,
// capped at 3 (covers the whole screen for ultra-degenerate faces).
__global__ __launch_bounds__(256) void bin_kernel(
    const float* __restrict__ faces, int* __restrict__ counts,
    int* __restrict__ lists, int B, int F)
{
    const int gid = blockIdx.x * 256 + threadIdx.x;
    if (gid >= B * F) return;
    const int b = gid / F, f = gid - b * F;
    const float* fp = faces + (size_t)gid * 9;
    const float x0 = fp[0], y0 = fp[1];
    const float x1 = fp[3], y1 = fp[4];
    const float x2 = fp[6], y2 = fp[7];
    // det for dilation only — plain math is fine (conservative use).
    const float det = (x1 - x0) * (y2 - y0) - (x2 - x0) * (y1 - y0);
    const float d = 2e-3f + fminf(1e-6f / fmaxf(fabsf(det), 1e-9f), 3.0f);
    const float lox = fminf(x0, fminf(x1, x2)) - d;
    const float hix = fmaxf(x0, fmaxf(x1, x2)) + d;
    const float loy = fminf(y0, fminf(y1, y2)) - d;
    const float hiy = fmaxf(y0, fmaxf(y1, y2)) + d;
    // tile t spans NDC [(32t+1-256)/256, (32t+31-256)/256]
    int tx0 = (int)ceilf ((256.f * lox + 225.f) * (1.f / 32.f));
    int tx1 = (int)floorf((256.f * hix + 255.f) * (1.f / 32.f));
    int ty0 = (int)ceilf ((256.f * loy + 225.f) * (1.f / 32.f));
    int ty1 = (int)floorf((256.f * hiy + 255.f) * (1.f / 32.f));
    tx0 = max(tx0, 0); tx1 = min(tx1, 15);
    ty0 = max(ty0, 0); ty1 = min(ty1, 15);
    for (int ty = ty0; ty <= ty1; ++ty)
        for (int tx = tx0; tx <= tx1; ++tx) {
            const int t = (b * 16 + ty) * 16 + tx;
            const int pos = atomicAdd(&counts[t], 1);
            if (pos < CAP) lists[(size_t)t * CAP + pos] = f;
        }
}

// ---------- pass 2: rasterize each tile from its bin ----------
// Numerics (verified R6): C = fma(xa,yb,-(xb*ya)); w = fma(yp,A, xp*B)+C;
// everything else per-op IEEE f32 in source order (barriered).
// Tie-break: smallest zp, then smallest face index (== reference's chunked
// argmin + strict-better scan, independent of bin order).
__global__ __launch_bounds__(256) void raster_kernel(
    const float* __restrict__ faces,     // (B, F, 3, 3)
    const float* __restrict__ textures,  // (B, F, 4, 4, 4, 3)
    const int*   __restrict__ counts,
    const int*   __restrict__ lists,
    float* __restrict__ out,             // (B, 256, 256, 5)
    int B, int F)
{
    const int tid  = threadIdx.x;
    const int b    = blockIdx.x >> 8;
    const int tile = blockIdx.x & 255;
    const int px   = (tile & 15) * 16 + (tid & 15);
    const int py   = (tile >> 4) * 16 + (tid >> 4);
    const float xp = (float)(2 * px + 1 - IS) * (1.0f / IS);  // exact (/2^8)
    const float yp = (float)(2 * py + 1 - IS) * (1.0f / IS);  // exact

    __shared__ float4 s_a[256];   // A0,B0,C0,A1
    __shared__ float4 s_b[256];   // B1,C1,A2,B2
    __shared__ float4 s_c[256];   // C2,z0,z1,z2
    __shared__ int    s_idx[256];

    float bestz = FARP;
    int   besti = -1;

    const float* fbase = faces + (size_t)b * F * 9;
    const int cnt = min(counts[blockIdx.x], CAP);
    const int* mylist = lists + (size_t)blockIdx.x * CAP;

    for (int cbase = 0; cbase < cnt; cbase += 256) {
        const int m = min(cnt - cbase, 256);
        if (tid < m) {
            const int f = mylist[cbase + tid];
            const float* fp = fbase + (size_t)f * 9;
            const float x0 = fp[0], y0 = fp[1], z0 = fp[2];
            const float x1 = fp[3], y1 = fp[4], z1 = fp[5];
            const float x2 = fp[6], y2 = fp[7], z2 = fp[8];
            const float A0 = subrn(x2, x1), B0 = subrn(y1, y2);
            const float C0 = fmarn(x1, y2, -mulrn(x2, y1));
            const float A1 = subrn(x0, x2), B1 = subrn(y2, y0);
            const float C1 = fmarn(x2, y0, -mulrn(x0, y2));
            const float A2 = subrn(x1, x0), B2 = subrn(y0, y1);
            const float C2 = fmarn(x0, y1, -mulrn(x1, y0));
            s_a[tid] = make_float4(A0, B0, C0, A1);
            s_b[tid] = make_float4(B1, C1, A2, B2);
            s_c[tid] = make_float4(C2, z0, z1, z2);
            s_idx[tid] = f;
        }
        __syncthreads();

        for (int j = 0; j < m; ++j) {
            const float4 fa = s_a[j];
            const float4 fb = s_b[j];
            const float4 fc = s_c[j];
            // Contracted: w = fma(yp, A, xp*B) + C
            const float w0 = addrn(fmarn(yp, fa.x, mulrn(xp, fa.y)), fa.z);
            const float w1 = addrn(fmarn(yp, fa.w, mulrn(xp, fb.x)), fb.y);
            const float w2 = addrn(fmarn(yp, fb.z, mulrn(xp, fb.w)), fc.x);
            const float det = addrn(addrn(w0, w1), w2);
            bool ins;
            if (det > TINYF)       ins = (w0 > 0.f) && (w1 > 0.f) && (w2 > 0.f);
            else if (det < -TINYF) ins = (w0 < 0.f) && (w1 < 0.f) && (w2 < 0.f);
            else                   ins = false;
            if (ins) {
                float n0 = divrn(w0, det), n1 = divrn(w1, det), n2 = divrn(w2, det);
                n0 = frn(fminf(fmaxf(n0, 0.f), 1.f));
                n1 = frn(fminf(fmaxf(n1, 0.f), 1.f));
                n2 = frn(fminf(fmaxf(n2, 0.f), 1.f));
                float s = addrn(addrn(n0, n1), n2);
                s = (s > TINYF) ? s : 1.0f;
                n0 = divrn(n0, s); n1 = divrn(n1, s); n2 = divrn(n2, s);
                float iz = addrn(addrn(divrn(n0, fc.y), divrn(n1, fc.z)),
                                 divrn(n2, fc.w));
                iz = (fabsf(iz) > TINYF) ? iz : 1.0f;
                const float zp = divrn(1.0f, iz);
                if (zp > NEARP && zp < FARP) {
                    const int fi = s_idx[j];
                    if (zp < bestz || (zp == bestz && fi < besti)) {
                        bestz = zp;
                        besti = fi;
                    }
                }
            }
        }
        __syncthreads();
    }

    // Phase C: shade the winning face (same contracted chain).
    float r = 0.f, g = 0.f, bch = 0.f, alpha = 0.f, depth = FARP;
    if (besti >= 0) {
        const float* fp = fbase + (size_t)besti * 9;
        const float x0 = fp[0], y0 = fp[1], z0 = fp[2];
        const float x1 = fp[3], y1 = fp[4], z1 = fp[5];
        const float x2 = fp[6], y2 = fp[7], z2 = fp[8];
        const float w0 = addrn(fmarn(yp, subrn(x2, x1), mulrn(xp, subrn(y1, y2))),
                               fmarn(x1, y2, -mulrn(x2, y1)));
        const float w1 = addrn(fmarn(yp, subrn(x0, x2), mulrn(xp, subrn(y2, y0))),
                               fmarn(x2, y0, -mulrn(x0, y2)));
        const float w2 = addrn(fmarn(yp, subrn(x1, x0), mulrn(xp, subrn(y0, y1))),
                               fmarn(x0, y1, -mulrn(x1, y0)));
        const float det = addrn(addrn(w0, w1), w2);
        const float sd = (fabsf(det) > TINYF) ? det : 1.0f;
        float n0 = divrn(w0, sd), n1 = divrn(w1, sd), n2 = divrn(w2, sd);
        n0 = frn(fminf(fmaxf(n0, 0.f), 1.f));
        n1 = frn(fminf(fmaxf(n1, 0.f), 1.f));
        n2 = frn(fminf(fmaxf(n2, 0.f), 1.f));
        float s = addrn(addrn(n0, n1), n2);
        s = (s > TINYF) ? s : 1.0f;
        n0 = divrn(n0, s); n1 = divrn(n1, s); n2 = divrn(n2, s);
        float iz = addrn(addrn(divrn(n0, z0), divrn(n1, z1)), divrn(n2, z2));
        iz = (fabsf(iz) > TINYF) ? iz : 1.0f;
        const float zp = divrn(1.0f, iz);
        depth = zp;

        const float t0 = fminf(fmaxf(divrn(mulrn(mulrn(n0, 3.0f), zp), z0), 0.f), 2.999f);
        const float t1 = fminf(fmaxf(divrn(mulrn(mulrn(n1, 3.0f), zp), z1), 0.f), 2.999f);
        const float t2 = fminf(fmaxf(divrn(mulrn(mulrn(n2, 3.0f), zp), z2), 0.f), 2.999f);
        const float l0 = floorf(t0), l1 = floorf(t1), l2 = floorf(t2);
        const float fr0 = subrn(t0, l0), fr1 = subrn(t1, l1), fr2 = subrn(t2, l2);
        const int i0 = (int)l0, i1 = (int)l1, i2 = (int)l2;

        const float* tx = textures + (size_t)(b * F + besti) * 64 * 3;
        for (int d0 = 0; d0 < 2; ++d0)
            for (int d1 = 0; d1 < 2; ++d1)
                for (int d2 = 0; d2 < 2; ++d2) {
                    const float wg = mulrn(mulrn(d0 ? fr0 : subrn(1.0f, fr0),
                                                 d1 ? fr1 : subrn(1.0f, fr1)),
                                           d2 ? fr2 : subrn(1.0f, fr2));
                    const float* tp = tx + ((i0 + d0) * 16 + (i1 + d1) * 4 + (i2 + d2)) * 3;
                    r   = addrn(r,   mulrn(wg, tp[0]));
                    g   = addrn(g,   mulrn(wg, tp[1]));
                    bch = addrn(bch, mulrn(wg, tp[2]));
                }
        alpha = 1.0f;
    }

    float* op = out + (((size_t)b * IS + py) * IS + px) * 5;
    op[0] = r;
    op[1] = g;
    op[2] = bch;
    op[3] = alpha;
    op[4] = depth;
}

extern "C" void kernel_launch(void* const* d_in, const int* in_sizes, int n_in,
                              void* d_out, int out_size, void* d_ws, size_t ws_size,
                              hipStream_t stream) {
    const float* faces    = (const float*)d_in[0];
    const float* textures = (const float*)d_in[1];
    float* out = (float*)d_out;
    const int F = FCOUNT;
    const int B = in_sizes[0] / (F * 9);
    const int ntiles = B * 256;

    int* counts = (int*)d_ws;                    // ntiles ints
    int* lists  = counts + ntiles;               // ntiles*CAP ints (~1 MB @ B=4)

    zero_counts<<<dim3(B), dim3(256), 0, stream>>>(counts);
    bin_kernel<<<dim3((B * F + 255) / 256), dim3(256), 0, stream>>>(
        faces, counts, lists, B, F);
    raster_kernel<<<dim3(ntiles), dim3(256), 0, stream>>>(
        faces, textures, counts, lists, out, B, F);
}

// Round 9
// 109.857 us; speedup vs baseline: 1.5873x; 1.5873x over previous
//
#include <hip/hip_runtime.h>

#define IS 256
#define FCOUNT 4096
#define NEARP 0.1f
#define FARP 100.0f
#define TINYF 1e-12f
#define CAP 256          // per-tile bin capacity (mean ~85, tail ≪ CAP — R8 validated)
#define GCAP 128         // per-image sliver-list capacity (expect ~<16)
#define DET_GLOBAL 1e-5f // |det| below this -> global list (escape can cross tiles)

// Value barrier: pins a value in a VGPR; no transform across it.
__device__ __forceinline__ float frn(float r) { asm("" : "+v"(r)); return r; }
__device__ __forceinline__ float mulrn(float a, float b) { return frn(a * b); }
__device__ __forceinline__ float addrn(float a, float b) { return frn(a + b); }
__device__ __forceinline__ float subrn(float a, float b) { return frn(a - b); }
__device__ __forceinline__ float divrn(float a, float b) { return frn(a / b); }
__device__ __forceinline__ float fmarn(float a, float b, float c) {
    return frn(__builtin_fmaf(a, b, c));
}

// ---------- pass 0: zero per-tile and per-image counters ----------
__global__ void zero_counts(int* __restrict__ counts, int* __restrict__ gcount) {
    counts[blockIdx.x * 256 + threadIdx.x] = 0;
    if (threadIdx.x == 0) gcount[blockIdx.x] = 0;
}

// ---------- pass 1: bin faces into 16x16-pixel tiles ----------
// Escape bound: fp-inside region extends <= w_err*diam/|det| ~ 6e-8/|det|
// beyond the true triangle. |det| >= 1e-5 -> dilate by 2e-3 + 3e-7/|det|
// (5x safety, <= 0.032 -> loop <= ~3x3 tiles). |det| < 1e-5 -> one atomic
// into the per-image global list (scanned by every tile) — avoids the R8
// pathology of 256 serialized atomics per sliver lane.
__global__ __launch_bounds__(256) void bin_kernel(
    const float* __restrict__ faces, int* __restrict__ counts,
    int* __restrict__ lists, int* __restrict__ gcount,
    int* __restrict__ glist, int B, int F)
{
    const int gid = blockIdx.x * 256 + threadIdx.x;
    if (gid >= B * F) return;
    const int b = gid / F, f = gid - b * F;
    const float* fp = faces + (size_t)gid * 9;
    const float x0 = fp[0], y0 = fp[1];
    const float x1 = fp[3], y1 = fp[4];
    const float x2 = fp[6], y2 = fp[7];
    const float det = (x1 - x0) * (y2 - y0) - (x2 - x0) * (y1 - y0);
    const float ad = fabsf(det);
    if (ad < DET_GLOBAL) {
        const int pos = atomicAdd(&gcount[b], 1);
        if (pos < GCAP) glist[b * GCAP + pos] = f;
        return;
    }
    const float d = 2e-3f + 3e-7f / ad;   // <= 0.032
    const float lox = fminf(x0, fminf(x1, x2)) - d;
    const float hix = fmaxf(x0, fmaxf(x1, x2)) + d;
    const float loy = fminf(y0, fminf(y1, y2)) - d;
    const float hiy = fmaxf(y0, fmaxf(y1, y2)) + d;
    // tile t spans NDC [(32t+1-256)/256, (32t+31-256)/256]
    int tx0 = (int)floorf((256.f * lox + 255.f) * (1.f / 32.f));
    int tx1 = (int)floorf((256.f * hix + 255.f) * (1.f / 32.f));
    int ty0 = (int)floorf((256.f * loy + 255.f) * (1.f / 32.f));
    int ty1 = (int)floorf((256.f * hiy + 255.f) * (1.f / 32.f));
    tx0 = max(tx0, 0); tx1 = min(tx1, 15);
    ty0 = max(ty0, 0); ty1 = min(ty1, 15);
    for (int ty = ty0; ty <= ty1; ++ty)
        for (int tx = tx0; tx <= tx1; ++tx) {
            const int t = (b * 16 + ty) * 16 + tx;
            const int pos = atomicAdd(&counts[t], 1);
            if (pos < CAP) lists[(size_t)t * CAP + pos] = f;
        }
}

// ---------- pass 2: rasterize each tile from its bin + image sliver list ----
// Numerics (verified R6): C = fma(xa,yb,-(xb*ya)); w = fma(yp,A, xp*B)+C;
// everything else per-op IEEE f32 in source order (barriered).
// Tie-break: smallest zp, then smallest face index (== reference's chunked
// argmin + strict-better scan, independent of bin order).
__global__ __launch_bounds__(256) void raster_kernel(
    const float* __restrict__ faces,     // (B, F, 3, 3)
    const float* __restrict__ textures,  // (B, F, 4, 4, 4, 3)
    const int*   __restrict__ counts,
    const int*   __restrict__ lists,
    const int*   __restrict__ gcount,
    const int*   __restrict__ glist,
    float* __restrict__ out,             // (B, 256, 256, 5)
    int B, int F)
{
    const int tid  = threadIdx.x;
    const int b    = blockIdx.x >> 8;
    const int tile = blockIdx.x & 255;
    const int px   = (tile & 15) * 16 + (tid & 15);
    const int py   = (tile >> 4) * 16 + (tid >> 4);
    const float xp = (float)(2 * px + 1 - IS) * (1.0f / IS);  // exact (/2^8)
    const float yp = (float)(2 * py + 1 - IS) * (1.0f / IS);  // exact

    __shared__ float4 s_a[256];   // A0,B0,C0,A1
    __shared__ float4 s_b[256];   // B1,C1,A2,B2
    __shared__ float4 s_c[256];   // C2,z0,z1,z2
    __shared__ int    s_idx[256];

    float bestz = FARP;
    int   besti = -1;

    const float* fbase = faces + (size_t)b * F * 9;
    const int cnt  = min(counts[blockIdx.x], CAP);
    const int gcnt = min(gcount[b], GCAP);
    const int total = cnt + gcnt;
    const int* mylist = lists + (size_t)blockIdx.x * CAP;
    const int* gl     = glist + b * GCAP;

    for (int cbase = 0; cbase < total; cbase += 256) {
        const int m = min(total - cbase, 256);
        if (tid < m) {
            const int k = cbase + tid;
            const int f = (k < cnt) ? mylist[k] : gl[k - cnt];
            const float* fp = fbase + (size_t)f * 9;
            const float x0 = fp[0], y0 = fp[1], z0 = fp[2];
            const float x1 = fp[3], y1 = fp[4], z1 = fp[5];
            const float x2 = fp[6], y2 = fp[7], z2 = fp[8];
            const float A0 = subrn(x2, x1), B0 = subrn(y1, y2);
            const float C0 = fmarn(x1, y2, -mulrn(x2, y1));
            const float A1 = subrn(x0, x2), B1 = subrn(y2, y0);
            const float C1 = fmarn(x2, y0, -mulrn(x0, y2));
            const float A2 = subrn(x1, x0), B2 = subrn(y0, y1);
            const float C2 = fmarn(x0, y1, -mulrn(x1, y0));
            s_a[tid] = make_float4(A0, B0, C0, A1);
            s_b[tid] = make_float4(B1, C1, A2, B2);
            s_c[tid] = make_float4(C2, z0, z1, z2);
            s_idx[tid] = f;
        }
        __syncthreads();

        for (int j = 0; j < m; ++j) {
            const float4 fa = s_a[j];
            const float4 fb = s_b[j];
            const float4 fc = s_c[j];
            // Contracted: w = fma(yp, A, xp*B) + C
            const float w0 = addrn(fmarn(yp, fa.x, mulrn(xp, fa.y)), fa.z);
            const float w1 = addrn(fmarn(yp, fa.w, mulrn(xp, fb.x)), fb.y);
            const float w2 = addrn(fmarn(yp, fb.z, mulrn(xp, fb.w)), fc.x);
            const float det = addrn(addrn(w0, w1), w2);
            bool ins;
            if (det > TINYF)       ins = (w0 > 0.f) && (w1 > 0.f) && (w2 > 0.f);
            else if (det < -TINYF) ins = (w0 < 0.f) && (w1 < 0.f) && (w2 < 0.f);
            else                   ins = false;
            if (ins) {
                float n0 = divrn(w0, det), n1 = divrn(w1, det), n2 = divrn(w2, det);
                n0 = frn(fminf(fmaxf(n0, 0.f), 1.f));
                n1 = frn(fminf(fmaxf(n1, 0.f), 1.f));
                n2 = frn(fminf(fmaxf(n2, 0.f), 1.f));
                float s = addrn(addrn(n0, n1), n2);
                s = (s > TINYF) ? s : 1.0f;
                n0 = divrn(n0, s); n1 = divrn(n1, s); n2 = divrn(n2, s);
                float iz = addrn(addrn(divrn(n0, fc.y), divrn(n1, fc.z)),
                                 divrn(n2, fc.w));
                iz = (fabsf(iz) > TINYF) ? iz : 1.0f;
                const float zp = divrn(1.0f, iz);
                if (zp > NEARP && zp < FARP) {
                    const int fi = s_idx[j];
                    if (zp < bestz || (zp == bestz && fi < besti)) {
                        bestz = zp;
                        besti = fi;
                    }
                }
            }
        }
        __syncthreads();
    }

    // Phase C: shade the winning face (same contracted chain).
    float r = 0.f, g = 0.f, bch = 0.f, alpha = 0.f, depth = FARP;
    if (besti >= 0) {
        const float* fp = fbase + (size_t)besti * 9;
        const float x0 = fp[0], y0 = fp[1], z0 = fp[2];
        const float x1 = fp[3], y1 = fp[4], z1 = fp[5];
        const float x2 = fp[6], y2 = fp[7], z2 = fp[8];
        const float w0 = addrn(fmarn(yp, subrn(x2, x1), mulrn(xp, subrn(y1, y2))),
                               fmarn(x1, y2, -mulrn(x2, y1)));
        const float w1 = addrn(fmarn(yp, subrn(x0, x2), mulrn(xp, subrn(y2, y0))),
                               fmarn(x2, y0, -mulrn(x0, y2)));
        const float w2 = addrn(fmarn(yp, subrn(x1, x0), mulrn(xp, subrn(y0, y1))),
                               fmarn(x0, y1, -mulrn(x1, y0)));
        const float det = addrn(addrn(w0, w1), w2);
        const float sd = (fabsf(det) > TINYF) ? det : 1.0f;
        float n0 = divrn(w0, sd), n1 = divrn(w1, sd), n2 = divrn(w2, sd);
        n0 = frn(fminf(fmaxf(n0, 0.f), 1.f));
        n1 = frn(fminf(fmaxf(n1, 0.f), 1.f));
        n2 = frn(fminf(fmaxf(n2, 0.f), 1.f));
        float s = addrn(addrn(n0, n1), n2);
        s = (s > TINYF) ? s : 1.0f;
        n0 = divrn(n0, s); n1 = divrn(n1, s); n2 = divrn(n2, s);
        float iz = addrn(addrn(divrn(n0, z0), divrn(n1, z1)), divrn(n2, z2));
        iz = (fabsf(iz) > TINYF) ? iz : 1.0f;
        const float zp = divrn(1.0f, iz);
        depth = zp;

        const float t0 = fminf(fmaxf(divrn(mulrn(mulrn(n0, 3.0f), zp), z0), 0.f), 2.999f);
        const float t1 = fminf(fmaxf(divrn(mulrn(mulrn(n1, 3.0f), zp), z1), 0.f), 2.999f);
        const float t2 = fminf(fmaxf(divrn(mulrn(mulrn(n2, 3.0f), zp), z2), 0.f), 2.999f);
        const float l0 = floorf(t0), l1 = floorf(t1), l2 = floorf(t2);
        const float fr0 = subrn(t0, l0), fr1 = subrn(t1, l1), fr2 = subrn(t2, l2);
        const int i0 = (int)l0, i1 = (int)l1, i2 = (int)l2;

        const float* tx = textures + (size_t)(b * F + besti) * 64 * 3;
        for (int d0 = 0; d0 < 2; ++d0)
            for (int d1 = 0; d1 < 2; ++d1)
                for (int d2 = 0; d2 < 2; ++d2) {
                    const float wg = mulrn(mulrn(d0 ? fr0 : subrn(1.0f, fr0),
                                                 d1 ? fr1 : subrn(1.0f, fr1)),
                                           d2 ? fr2 : subrn(1.0f, fr2));
                    const float* tp = tx + ((i0 + d0) * 16 + (i1 + d1) * 4 + (i2 + d2)) * 3;
                    r   = addrn(r,   mulrn(wg, tp[0]));
                    g   = addrn(g,   mulrn(wg, tp[1]));
                    bch = addrn(bch, mulrn(wg, tp[2]));
                }
        alpha = 1.0f;
    }

    float* op = out + (((size_t)b * IS + py) * IS + px) * 5;
    op[0] = r;
    op[1] = g;
    op[2] = bch;
    op[3] = alpha;
    op[4] = depth;
}

extern "C" void kernel_launch(void* const* d_in, const int* in_sizes, int n_in,
                              void* d_out, int out_size, void* d_ws, size_t ws_size,
                              hipStream_t stream) {
    const float* faces    = (const float*)d_in[0];
    const float* textures = (const float*)d_in[1];
    float* out = (float*)d_out;
    const int F = FCOUNT;
    const int B = in_sizes[0] / (F * 9);
    const int ntiles = B * 256;

    int* counts = (int*)d_ws;                    // ntiles ints
    int* gcount = counts + ntiles;               // B ints
    int* glist  = gcount + B;                    // B*GCAP ints
    int* lists  = glist + B * GCAP;              // ntiles*CAP ints (~1 MB @ B=4)

    zero_counts<<<dim3(B), dim3(256), 0, stream>>>(counts, gcount);
    bin_kernel<<<dim3((B * F + 255) / 256), dim3(256), 0, stream>>>(
        faces, counts, lists, gcount, glist, B, F);
    raster_kernel<<<dim3(ntiles), dim3(256), 0, stream>>>(
        faces, textures, counts, lists, gcount, glist, out, B, F);
}